// Round 14
// baseline (246.995 us; speedup 1.0000x reference)
//
#include <hip/hip_runtime.h>

// SSIM over (32,3,512,512) fp32 pairs, 11x11 gaussian sigma=1.5, VALID conv,
// scalar mean output. Fused separable conv; v-stats in LDS as CHANNEL-PAIR
// vf2 arrays (A=(mu1,mu2), B=(ee,e12)); packed horizontal conv; SSIM + mean.
//
// R10: instruction diet. R9 showed issue-fat (736 instr/thread-iter vs ~420
// countable; 188/px vs ~55 math floor) with busy 55% at 8 waves. Cuts:
// (1) full unroll + circular window slot (2u+j)%12 — kills 40 shift movs/iter;
// (2) channel-pair LDS: phase-H conv = 88 pk_fma (was 176 scalar), no
// alignment tricks (packed axis = channel). Costs: ~16 transpose movs at
// write, VGPR ~95-110 under launch_bounds(256,2) (cap 128, no spill) ->
// 4-5 waves/SIMD (was 8); R9 says wave loss costs few busy points vs -21%
// instr. LDS 17.4KB unchanged, same quad XOR swizzle. RPB=24, grid 2016.

namespace {
constexpr int IMG_H = 512;
constexpr int IMG_W = 512;
constexpr int NIMG  = 96;            // B*C = 32*3
constexpr int OUT_H = 502;
constexpr int OUT_W = 502;
constexpr int RPB   = 24;            // output rows per block (21 x-blocks = 2016)
constexpr int QR    = 2;             // output rows per inner iteration
constexpr int WIN   = QR + 10;       // circular window rows (12)
constexpr int NQ    = 272;           // 16B quads per (array, q-row): 2 cols/quad
constexpr double TOTAL = 24192384.0; // 96*502*502

// exp(-k^2/4.5) for k=5..1, normalized at compile time
constexpr double U0 = 0.0038659201;
constexpr double U1 = 0.0285655007;
constexpr double U2 = 0.1353352832366127;
constexpr double U3 = 0.4111122898;
constexpr double U4 = 0.8007374026;
constexpr double S  = 1.0 + 2.0 * (U0 + U1 + U2 + U3 + U4);
}

typedef float vf2 __attribute__((ext_vector_type(2)));
typedef float vf4 __attribute__((ext_vector_type(4)));

__device__ __forceinline__ vf2 pk_fma(float w, vf2 a, vf2 c) {
    vf2 wv = {w, w};
    return __builtin_elementwise_fma(wv, a, c);   // -> v_pk_fma_f32
}

__global__ __launch_bounds__(256, 2) void ssim_main(const float* __restrict__ img1,
                                                    const float* __restrict__ img2,
                                                    double* __restrict__ acc)
{
    // channel-pair v-stat arrays: per column c, ldsA holds (mu1,mu2), ldsB (ee,e12)
    __shared__ __align__(16) float ldsA[QR][NQ * 4];   // 8704 B
    __shared__ __align__(16) float ldsB[QR][NQ * 4];   // 8704 B
    __shared__ float red[4];

    const float g[11] = {
        (float)(U0/S), (float)(U1/S), (float)(U2/S), (float)(U3/S), (float)(U4/S),
        (float)(1.0/S),
        (float)(U4/S), (float)(U3/S), (float)(U2/S), (float)(U1/S), (float)(U0/S)
    };
    constexpr float C1 = 1e-4f;   // 0.01^2
    constexpr float C2 = 9e-4f;   // 0.03^2

    const int t   = threadIdx.x;
    const int z   = blockIdx.y;
    const int oy0 = blockIdx.x * RPB;
    const int row_end = min(oy0 + RPB, OUT_H);

    const vf2* p1 = (const vf2*)(img1 + (size_t)z * (IMG_H * IMG_W)) + t;
    const vf2* p2 = (const vf2*)(img2 + (size_t)z * (IMG_H * IMG_W)) + t;

    // phase-V: thread owns cols 2t,2t+1 = quad t. Swizzled write offset (floats).
    const int woff = (t ^ ((t >> 3) & 7)) << 2;

    // phase-H: thread = (row hq 0..1, 4-col group at cb). Swizzled quad offsets.
    const int hq = t >> 7;            // 0..1, all 256 threads active
    const int cb = (t & 127) << 2;    // 0..508
    const int qb = (t & 127) << 1;    // first quad (cols cb, cb+1)
    int roff[7];
    #pragma unroll
    for (int m = 0; m < 7; ++m) {
        const int q = qb + m;         // <= 261 < 272
        roff[m] = (q ^ ((q >> 3) & 7)) << 2;
    }

    // circular window: slot m holds row oy0 + (m mod 12 congruent). Init rows 0..9.
    vf2 wx[WIN], wy[WIN];
    #pragma unroll
    for (int j = 0; j < WIN - QR; ++j) {
        wx[j] = p1[(oy0 + j) * (IMG_W / 2)];
        wy[j] = p2[(oy0 + j) * (IMG_W / 2)];
    }

    float local = 0.f;

    #pragma unroll
    for (int u = 0; u < RPB / QR; ++u) {
        const int r0 = oy0 + u * QR;
        if (r0 >= row_end) break;

        // ---- load the 2 new window rows into circular slots ----
        #pragma unroll
        for (int i = 0; i < QR; ++i) {
            const int slot = (2 * u + 10 + i) % WIN;
            const int row  = min(r0 + 10 + i, IMG_H - 1);   // clamp: tail only
            wx[slot] = p1[row * (IMG_W / 2)];
            wy[slot] = p2[row * (IMG_W / 2)];
        }

        // ---- phase V: vertical 11-tap conv, packed, 4 channels ----
        vf2 am1[QR], am2[QR], app[QR], axy[QR];
        #pragma unroll
        for (int q = 0; q < QR; ++q) {
            am1[q] = (vf2){0.f, 0.f};
            am2[q] = (vf2){0.f, 0.f};
            app[q] = (vf2){0.f, 0.f};
            axy[q] = (vf2){0.f, 0.f};
        }
        #pragma unroll
        for (int j = 0; j < WIN; ++j) {
            const int slot = (2 * u + j) % WIN;
            const vf2 x = wx[slot], y = wy[slot];
            const vf2 pp = __builtin_elementwise_fma(y, y, x * x);  // x^2 + y^2
            const vf2 xy = x * y;
            #pragma unroll
            for (int q = 0; q < QR; ++q) {
                const int k = j - q;
                if (k >= 0 && k < 11) {
                    const float w = g[k];
                    am1[q] = pk_fma(w, x,  am1[q]);
                    am2[q] = pk_fma(w, y,  am2[q]);
                    app[q] = pk_fma(w, pp, app[q]);
                    axy[q] = pk_fma(w, xy, axy[q]);
                }
            }
        }
        __syncthreads();   // previous iteration's phase-H reads complete
        #pragma unroll
        for (int q = 0; q < QR; ++q) {
            // transpose (channel, col) -> channel-pair quads at write time
            vf4 qa = {am1[q].x, am2[q].x, am1[q].y, am2[q].y};
            vf4 qbv = {app[q].x, axy[q].x, app[q].y, axy[q].y};
            *(vf4*)&ldsA[q][woff] = qa;
            *(vf4*)&ldsB[q][woff] = qbv;
        }
        __syncthreads();   // v-stats visible

        // ---- phase H: packed 11-tap conv on channel pairs + SSIM, 4 cols ----
        if (r0 + hq < row_end && cb < OUT_W) {
            vf2 sA[4], sB[4];
            {
                vf4 fq[7];
                #pragma unroll
                for (int m = 0; m < 7; ++m) fq[m] = *(const vf4*)&ldsA[hq][roff[m]];
                #pragma unroll
                for (int j = 0; j < 4; ++j) {
                    vf2 s = (vf2){0.f, 0.f};
                    #pragma unroll
                    for (int k = 0; k < 11; ++k) {
                        const int c = j + k;
                        const vf2 f = (c & 1) ? fq[c >> 1].zw : fq[c >> 1].xy;
                        s = pk_fma(g[k], f, s);
                    }
                    sA[j] = s;
                }
            }
            {
                vf4 fq[7];
                #pragma unroll
                for (int m = 0; m < 7; ++m) fq[m] = *(const vf4*)&ldsB[hq][roff[m]];
                #pragma unroll
                for (int j = 0; j < 4; ++j) {
                    vf2 s = (vf2){0.f, 0.f};
                    #pragma unroll
                    for (int k = 0; k < 11; ++k) {
                        const int c = j + k;
                        const vf2 f = (c & 1) ? fq[c >> 1].zw : fq[c >> 1].xy;
                        s = pk_fma(g[k], f, s);
                    }
                    sB[j] = s;
                }
            }
            #pragma unroll
            for (int j = 0; j < 4; ++j) {
                if (cb + j < OUT_W) {
                    const float mu1 = sA[j].x, mu2 = sA[j].y;
                    const float ee  = sB[j].x, e12 = sB[j].y;
                    const float mu11 = mu1 * mu1;
                    const float mu22 = mu2 * mu2;
                    const float mu12 = mu1 * mu2;
                    const float mm   = mu11 + mu22;
                    const float s12  = e12 - mu12;
                    const float spp  = ee - mm;          // s1 + s2
                    const float num = fmaf(2.f, mu12, C1) * fmaf(2.f, s12, C2);
                    const float den = (mm + C1) * (spp + C2);
                    local = fmaf(num, __builtin_amdgcn_rcpf(den), local);
                }
            }
        }
    }

    // ---------------- reduction: wave shuffle -> LDS -> double atomic ----------------
    #pragma unroll
    for (int off = 32; off > 0; off >>= 1) local += __shfl_down(local, off, 64);
    if ((t & 63) == 0) red[t >> 6] = local;
    __syncthreads();
    if (t == 0) {
        double s = (double)red[0] + (double)red[1] + (double)red[2] + (double)red[3];
        atomicAdd(acc, s);
    }
}

__global__ void ssim_fin(const double* __restrict__ acc, float* __restrict__ out)
{
    out[0] = (float)(acc[0] / TOTAL);
}

extern "C" void kernel_launch(void* const* d_in, const int* in_sizes, int n_in,
                              void* d_out, int out_size, void* d_ws, size_t ws_size,
                              hipStream_t stream)
{
    (void)in_sizes; (void)n_in; (void)out_size; (void)ws_size;
    const float* img1 = (const float*)d_in[0];
    const float* img2 = (const float*)d_in[1];
    double* acc = (double*)d_ws;

    hipMemsetAsync(d_ws, 0, sizeof(double), stream);
    dim3 grid((OUT_H + RPB - 1) / RPB, NIMG);   // 21 x 96 = 2016 blocks
    hipLaunchKernelGGL(ssim_main, grid, dim3(256), 0, stream, img1, img2, acc);
    hipLaunchKernelGGL(ssim_fin, dim3(1), dim3(1), 0, stream, acc, (float*)d_out);
}